// Round 3
// baseline (997.013 us; speedup 1.0000x reference)
//
#include <hip/hip_runtime.h>
#include <hip/hip_bf16.h>

#define N_NODES 100000
#define N_EDGES 3200000
#define DDIM    256
#define M_PAD   100096   // 782 * 128
#define NBKT    782      // buckets = dst >> 7 (128 dsts per bucket)
#define BCAP    4608     // mean 4096 + 8 sigma
#define EPB_A   4096     // edges per binA block
#define NPW     13       // nodes per gather wave (8192 waves * 13 >= 100000)
#define GBLK    2048     // gather blocks (x4 waves = 8192)

typedef __attribute__((ext_vector_type(8))) short short8;
typedef __attribute__((ext_vector_type(4))) float f32x4;

typedef const __attribute__((address_space(1))) void gvoid_t;
typedef __attribute__((address_space(3))) void lvoid_t;

__device__ __forceinline__ void load_lds16(const void* g, void* l) {
  __builtin_amdgcn_global_load_lds((gvoid_t*)g, (lvoid_t*)l, 16, 0, 0);
}

__device__ __forceinline__ unsigned short f2bf(float f) {
  __hip_bfloat16 h = __float2bfloat16(f);
  return *(unsigned short*)&h;
}
__device__ __forceinline__ float bflo(unsigned u) { return __uint_as_float(u << 16); }
__device__ __forceinline__ float bfhi(unsigned u) { return __uint_as_float(u & 0xffff0000u); }

// ---------------- convert X (fp32 -> bf16), 4 elems/thread ----------------
__global__ void conv_x_kernel(const float* __restrict__ x, unsigned short* __restrict__ xb) {
  size_t i = (size_t)blockIdx.x * blockDim.x + threadIdx.x;
  size_t idx = i * 4;
  if (idx >= (size_t)N_NODES * DDIM) return;
  float4 v = *(const float4*)(x + idx);
  ushort4 o;
  o.x = f2bf(v.x); o.y = f2bf(v.y); o.z = f2bf(v.z); o.w = f2bf(v.w);
  *(ushort4*)(xb + idx) = o;
}

// ------------- convert W (fp32 [K][N] -> bf16 transposed [N][K]) ----------
__global__ void conv_w_kernel(const float* __restrict__ w, unsigned short* __restrict__ wt) {
  int t = blockIdx.x * blockDim.x + threadIdx.x;   // 65536 threads
  int n = t >> 8, k = t & 255;
  wt[t] = f2bf(w[k * 256 + n]);                    // wt[n*256 + k]
}

// ---------------- MFMA GEMM: support = Xb @ Wt^T  (bf16 out) --------------
__global__ __launch_bounds__(256) void gemm_kernel(const unsigned short* __restrict__ xb,
                                                   const unsigned short* __restrict__ wt,
                                                   unsigned short* __restrict__ sup) {
  __shared__ unsigned short As[128 * 32];
  __shared__ unsigned short Bs[128 * 32];
  const int tid  = threadIdx.x;
  const int w    = tid >> 6;
  const int lane = tid & 63;
  const int quad = lane >> 4;
  const int l15  = lane & 15;
  const int wr   = w >> 1, wc = w & 1;
  const int m0 = blockIdx.x * 128;
  const int n0 = blockIdx.y * 128;

  f32x4 acc[4][4] = {};

  const int srow   = lane >> 2;
  const int schunk = (lane & 3) * 8;

  for (int kt = 0; kt < 256; kt += 32) {
#pragma unroll
    for (int i = 0; i < 2; ++i) {
      int r = w * 32 + i * 16 + srow;
      load_lds16(xb + ((size_t)(m0 + r) * 256 + kt + schunk),
                 As + (w * 32 + i * 16) * 32);
      load_lds16(wt + ((size_t)(n0 + r) * 256 + kt + schunk),
                 Bs + (w * 32 + i * 16) * 32);
    }
    __syncthreads();

    short8 a[4], b[4];
#pragma unroll
    for (int mi = 0; mi < 4; ++mi)
      a[mi] = *(const short8*)(As + (wr * 64 + mi * 16 + l15) * 32 + quad * 8);
#pragma unroll
    for (int ni = 0; ni < 4; ++ni)
      b[ni] = *(const short8*)(Bs + (wc * 64 + ni * 16 + l15) * 32 + quad * 8);

#pragma unroll
    for (int mi = 0; mi < 4; ++mi)
#pragma unroll
      for (int ni = 0; ni < 4; ++ni)
        acc[mi][ni] = __builtin_amdgcn_mfma_f32_16x16x32_bf16(a[mi], b[ni], acc[mi][ni], 0, 0, 0);
    __syncthreads();
  }

#pragma unroll
  for (int mi = 0; mi < 4; ++mi) {
#pragma unroll
    for (int r = 0; r < 4; ++r) {
      size_t row = (size_t)(m0 + wr * 64 + mi * 16 + quad * 4 + r);
#pragma unroll
      for (int ni = 0; ni < 4; ++ni) {
        int col = n0 + wc * 64 + ni * 16 + l15;
        sup[row * 256 + col] = f2bf(acc[mi][ni][r]);
      }
    }
  }
}

// ---- pass A: bin edges into 782 fixed-capacity bucket regions (coalesced) ----
// pack: [w:32][dstlow:7 @bit17][src:17]
__global__ __launch_bounds__(256) void binA_kernel(const int* __restrict__ src,
                                                   const int* __restrict__ dst,
                                                   const float* __restrict__ wgt,
                                                   int* __restrict__ gcur,
                                                   unsigned long long* __restrict__ region) {
  __shared__ unsigned long long staged[EPB_A];
  __shared__ unsigned short sbkt[EPB_A];
  __shared__ int lhist[NBKT];
  __shared__ int lstart[NBKT];
  __shared__ int lcur[NBKT];
  __shared__ int gb[NBKT];
  __shared__ int csum[256];

  const int t = threadIdx.x;
  const int e0 = blockIdx.x * EPB_A;
  const int ecnt = min(EPB_A, N_EDGES - e0);

  for (int i = t; i < NBKT; i += 256) lhist[i] = 0;
  __syncthreads();
  for (int k = t; k < ecnt; k += 256)
    atomicAdd(&lhist[dst[e0 + k] >> 7], 1);
  __syncthreads();

  int i0 = 4 * t;
  int a0 = (i0 + 0 < NBKT) ? lhist[i0 + 0] : 0;
  int a1 = (i0 + 1 < NBKT) ? lhist[i0 + 1] : 0;
  int a2 = (i0 + 2 < NBKT) ? lhist[i0 + 2] : 0;
  int a3 = (i0 + 3 < NBKT) ? lhist[i0 + 3] : 0;
  int s = a0 + a1 + a2 + a3;
  csum[t] = s;
  __syncthreads();
  for (int off = 1; off < 256; off <<= 1) {
    int v = (t >= off) ? csum[t - off] : 0;
    __syncthreads();
    csum[t] += v;
    __syncthreads();
  }
  int base = csum[t] - s;
  if (i0 + 0 < NBKT) lstart[i0 + 0] = base; base += a0;
  if (i0 + 1 < NBKT) lstart[i0 + 1] = base; base += a1;
  if (i0 + 2 < NBKT) lstart[i0 + 2] = base; base += a2;
  if (i0 + 3 < NBKT) lstart[i0 + 3] = base;
  __syncthreads();

  for (int i = t; i < NBKT; i += 256) {
    int c = lhist[i];
    int off = c ? atomicAdd(&gcur[i], c) : 0;
    gb[i] = i * BCAP + off;
    lcur[i] = lstart[i];
  }
  __syncthreads();

  for (int k = t; k < ecnt; k += 256) {
    int d  = dst[e0 + k];
    int sr = src[e0 + k];
    float w = wgt[e0 + k];
    int b = d >> 7;
    int p = atomicAdd(&lcur[b], 1);
    staged[p] = ((unsigned long long)__float_as_uint(w) << 32) |
                ((unsigned)(d & 127) << 17) | (unsigned)sr;
    sbkt[p] = (unsigned short)b;
  }
  __syncthreads();

  for (int j = t; j < ecnt; j += 256) {
    int b = sbkt[j];
    int addr = gb[b] + (j - lstart[b]);
    if (addr < (b + 1) * BCAP) region[addr] = staged[j];  // overflow guard (never fires)
  }
}

// ---- pass B: per-bucket counting sort by (dst_local:7, src_range:4) ------
__global__ __launch_bounds__(256) void csrB_kernel(unsigned long long* __restrict__ region,
                                                   const int* __restrict__ gcur,
                                                   int2* __restrict__ rowse) {
  __shared__ unsigned long long lcsr[BCAP];
  __shared__ int lhist[2048];
  __shared__ int csum[256];
  const int t = threadIdx.x;
  const int b = blockIdx.x;
  const int cnt = min(gcur[b], BCAP);
  const int base = b * BCAP;

  for (int i = t; i < 2048; i += 256) lhist[i] = 0;
  __syncthreads();
  for (int j = t; j < cnt; j += 256) {
    unsigned lo = (unsigned)region[base + j];
    int key = (int)((((lo >> 17) & 127) << 4) | ((lo >> 13) & 15));
    atomicAdd(&lhist[key], 1);
  }
  __syncthreads();
  // scan of 2048 counters; thread t owns [8t, 8t+8)
  int loc[8], s = 0;
#pragma unroll
  for (int j = 0; j < 8; ++j) { loc[j] = lhist[8 * t + j]; s += loc[j]; }
  csum[t] = s;
  __syncthreads();
  for (int off = 1; off < 256; off <<= 1) {
    int v = (t >= off) ? csum[t - off] : 0;
    __syncthreads();
    csum[t] += v;
    __syncthreads();
  }
  int run = csum[t] - s;
#pragma unroll
  for (int j = 0; j < 8; ++j) { lhist[8 * t + j] = run; run += loc[j]; }
  __syncthreads();
  // rowse from cell starts (before placement mutates lhist)
  if (t < 128) {
    int gd = b * 128 + t;
    if (gd < N_NODES) {
      int st = lhist[t * 16];
      int en = (t == 127) ? cnt : lhist[(t + 1) * 16];
      rowse[gd] = make_int2(base + st, base + en);
    }
  }
  __syncthreads();
  for (int j = t; j < cnt; j += 256) {
    unsigned long long e = region[base + j];
    unsigned lo = (unsigned)e;
    int key = (int)((((lo >> 17) & 127) << 4) | ((lo >> 13) & 15));
    int p = atomicAdd(&lhist[key], 1);
    lcsr[p] = e;
  }
  __syncthreads();
  for (int j = t; j < cnt; j += 256) region[base + j] = lcsr[j];
}

// ---- gather: 8192 waves, 13 nodes each, globally range-synchronized ------
__global__ __launch_bounds__(256) void gather_kernel(const unsigned long long* __restrict__ packed,
                                                     const int2* __restrict__ rowse,
                                                     const unsigned short* __restrict__ sup,
                                                     const float* __restrict__ bias,
                                                     float* __restrict__ out) {
  const int wid  = blockIdx.x * 4 + (threadIdx.x >> 6);
  const int lane = threadIdx.x & 63;
  const int c0   = lane * 4;
  const int n0   = wid * NPW;
  float4 bv = *(const float4*)(bias + c0);

  float a[NPW][4];
  int cur[NPW], en[NPW];
#pragma unroll
  for (int p = 0; p < NPW; ++p) {
    int n = n0 + p;
    if (n < N_NODES) { int2 se = rowse[n]; cur[p] = se.x; en[p] = se.y; }
    else             { cur[p] = 0; en[p] = 0; }
    a[p][0] = bv.x; a[p][1] = bv.y; a[p][2] = bv.z; a[p][3] = bv.w;
  }

  for (int r = 0; r < 16; ++r) {   // src ranges of 8192 rows; all waves walk in lockstep
#pragma unroll
    for (int p = 0; p < NPW; ++p) {
      int c = cur[p], e = en[p];
      while (c < e) {
        unsigned long long m = packed[c];
        int src = (int)(m & 0x1ffffu);
        if ((src >> 13) != r) break;
        float w = __uint_as_float((unsigned)(m >> 32));
        uint2 px = *(const uint2*)(sup + (size_t)src * 256 + c0);
        a[p][0] = fmaf(w, bflo(px.x), a[p][0]);
        a[p][1] = fmaf(w, bfhi(px.x), a[p][1]);
        a[p][2] = fmaf(w, bflo(px.y), a[p][2]);
        a[p][3] = fmaf(w, bfhi(px.y), a[p][3]);
        ++c;
      }
      cur[p] = c;
    }
  }

#pragma unroll
  for (int p = 0; p < NPW; ++p) {
    int n = n0 + p;
    if (n < N_NODES)
      *(float4*)(out + (size_t)n * 256 + c0) = make_float4(a[p][0], a[p][1], a[p][2], a[p][3]);
  }
}

extern "C" void kernel_launch(void* const* d_in, const int* in_sizes, int n_in,
                              void* d_out, int out_size, void* d_ws, size_t ws_size,
                              hipStream_t stream) {
  const float* x        = (const float*)d_in[0];
  const int*   edge_src = (const int*)d_in[1];
  const int*   edge_dst = (const int*)d_in[2];
  const float* edge_w   = (const float*)d_in[3];
  const float* weight   = (const float*)d_in[4];
  const float* bias     = (const float*)d_in[5];
  float* out = (float*)d_out;

  char* ws = (char*)d_ws;
  size_t off = 0;
  auto alloc = [&](size_t bytes) -> void* {
    void* p = ws + off;
    off = (off + bytes + 255) & ~(size_t)255;
    return p;
  };

  unsigned short* xb  = (unsigned short*)alloc((size_t)M_PAD * 256 * 2);  // 51.25 MB
  unsigned short* wt  = (unsigned short*)alloc(256 * 256 * 2);
  unsigned short* sup = (unsigned short*)alloc((size_t)M_PAD * 256 * 2);  // 51.25 MB

  // region/gcur/rowse alias xb (dead after gemm); region = 782*4608*8 = 28.84 MB
  char* xbb = (char*)xb;
  unsigned long long* region = (unsigned long long*)xbb;
  int*  gcur  = (int*)(xbb + (29u << 20));
  int2* rowse = (int2*)(xbb + (30u << 20));

  conv_x_kernel<<<25000, 256, 0, stream>>>(x, xb);
  conv_w_kernel<<<256, 256, 0, stream>>>(weight, wt);
  gemm_kernel<<<dim3(782, 2), 256, 0, stream>>>(xb, wt, sup);
  hipMemsetAsync(gcur, 0, NBKT * 4, stream);          // after gemm: gcur aliases xb
  binA_kernel<<<(N_EDGES + EPB_A - 1) / EPB_A, 256, 0, stream>>>(edge_src, edge_dst, edge_w,
                                                                 gcur, region);
  csrB_kernel<<<NBKT, 256, 0, stream>>>(region, gcur, rowse);
  gather_kernel<<<GBLK, 256, 0, stream>>>(region, rowse, sup, bias, out);
}

// Round 6
// 534.816 us; speedup vs baseline: 1.8642x; 1.8642x over previous
//
#include <hip/hip_runtime.h>
#include <hip/hip_bf16.h>

#define N_NODES 100000
#define N_EDGES 3200000
#define DDIM    256
#define M_PAD   100096   // 782 * 128
#define NBKT    782      // buckets = dst >> 7 (128 dsts per bucket)
#define BCAP    4608     // mean 4096 + 8 sigma
#define EPB_A   4096     // edges per binA block

typedef __attribute__((ext_vector_type(8))) short short8;
typedef __attribute__((ext_vector_type(4))) float f32x4;

typedef const __attribute__((address_space(1))) void gvoid_t;
typedef __attribute__((address_space(3))) void lvoid_t;

__device__ __forceinline__ void load_lds16(const void* g, void* l) {
  __builtin_amdgcn_global_load_lds((gvoid_t*)g, (lvoid_t*)l, 16, 0, 0);
}

__device__ __forceinline__ unsigned short f2bf(float f) {
  __hip_bfloat16 h = __float2bfloat16(f);
  return *(unsigned short*)&h;
}
__device__ __forceinline__ float bflo(unsigned u) { return __uint_as_float(u << 16); }
__device__ __forceinline__ float bfhi(unsigned u) { return __uint_as_float(u & 0xffff0000u); }

// ---------------- convert X (fp32 -> bf16), 4 elems/thread ----------------
__global__ void conv_x_kernel(const float* __restrict__ x, unsigned short* __restrict__ xb) {
  size_t i = (size_t)blockIdx.x * blockDim.x + threadIdx.x;
  size_t idx = i * 4;
  if (idx >= (size_t)N_NODES * DDIM) return;
  float4 v = *(const float4*)(x + idx);
  ushort4 o;
  o.x = f2bf(v.x); o.y = f2bf(v.y); o.z = f2bf(v.z); o.w = f2bf(v.w);
  *(ushort4*)(xb + idx) = o;
}

// ------------- convert W (fp32 [K][N] -> bf16 transposed [N][K]) ----------
__global__ void conv_w_kernel(const float* __restrict__ w, unsigned short* __restrict__ wt) {
  int t = blockIdx.x * blockDim.x + threadIdx.x;   // 65536 threads
  int n = t >> 8, k = t & 255;
  wt[t] = f2bf(w[k * 256 + n]);                    // wt[n*256 + k]
}

// ---------------- MFMA GEMM: support = Xb @ Wt^T  (bf16 out) --------------
__global__ __launch_bounds__(256) void gemm_kernel(const unsigned short* __restrict__ xb,
                                                   const unsigned short* __restrict__ wt,
                                                   unsigned short* __restrict__ sup) {
  __shared__ unsigned short As[128 * 32];
  __shared__ unsigned short Bs[128 * 32];
  const int tid  = threadIdx.x;
  const int w    = tid >> 6;
  const int lane = tid & 63;
  const int quad = lane >> 4;
  const int l15  = lane & 15;
  const int wr   = w >> 1, wc = w & 1;
  const int m0 = blockIdx.x * 128;
  const int n0 = blockIdx.y * 128;

  f32x4 acc[4][4] = {};

  const int srow   = lane >> 2;
  const int schunk = (lane & 3) * 8;

  for (int kt = 0; kt < 256; kt += 32) {
#pragma unroll
    for (int i = 0; i < 2; ++i) {
      int r = w * 32 + i * 16 + srow;
      load_lds16(xb + ((size_t)(m0 + r) * 256 + kt + schunk),
                 As + (w * 32 + i * 16) * 32);
      load_lds16(wt + ((size_t)(n0 + r) * 256 + kt + schunk),
                 Bs + (w * 32 + i * 16) * 32);
    }
    __syncthreads();

    short8 a[4], b[4];
#pragma unroll
    for (int mi = 0; mi < 4; ++mi)
      a[mi] = *(const short8*)(As + (wr * 64 + mi * 16 + l15) * 32 + quad * 8);
#pragma unroll
    for (int ni = 0; ni < 4; ++ni)
      b[ni] = *(const short8*)(Bs + (wc * 64 + ni * 16 + l15) * 32 + quad * 8);

#pragma unroll
    for (int mi = 0; mi < 4; ++mi)
#pragma unroll
      for (int ni = 0; ni < 4; ++ni)
        acc[mi][ni] = __builtin_amdgcn_mfma_f32_16x16x32_bf16(a[mi], b[ni], acc[mi][ni], 0, 0, 0);
    __syncthreads();
  }

#pragma unroll
  for (int mi = 0; mi < 4; ++mi) {
#pragma unroll
    for (int r = 0; r < 4; ++r) {
      size_t row = (size_t)(m0 + wr * 64 + mi * 16 + quad * 4 + r);
#pragma unroll
      for (int ni = 0; ni < 4; ++ni) {
        int col = n0 + wc * 64 + ni * 16 + l15;
        sup[row * 256 + col] = f2bf(acc[mi][ni][r]);
      }
    }
  }
}

// ---- pass A: bin edges into 782 fixed-capacity bucket regions (coalesced) ----
// pack: [w:32][dstlow:7 @bit17][src:17]
__global__ __launch_bounds__(256) void binA_kernel(const int* __restrict__ src,
                                                   const int* __restrict__ dst,
                                                   const float* __restrict__ wgt,
                                                   int* __restrict__ gcur,
                                                   unsigned long long* __restrict__ region) {
  __shared__ unsigned long long staged[EPB_A];
  __shared__ unsigned short sbkt[EPB_A];
  __shared__ int lhist[NBKT];
  __shared__ int lstart[NBKT];
  __shared__ int lcur[NBKT];
  __shared__ int gb[NBKT];
  __shared__ int csum[256];

  const int t = threadIdx.x;
  const int e0 = blockIdx.x * EPB_A;
  const int ecnt = min(EPB_A, N_EDGES - e0);

  for (int i = t; i < NBKT; i += 256) lhist[i] = 0;
  __syncthreads();
  for (int k = t; k < ecnt; k += 256)
    atomicAdd(&lhist[dst[e0 + k] >> 7], 1);
  __syncthreads();

  int i0 = 4 * t;
  int a0 = (i0 + 0 < NBKT) ? lhist[i0 + 0] : 0;
  int a1 = (i0 + 1 < NBKT) ? lhist[i0 + 1] : 0;
  int a2 = (i0 + 2 < NBKT) ? lhist[i0 + 2] : 0;
  int a3 = (i0 + 3 < NBKT) ? lhist[i0 + 3] : 0;
  int s = a0 + a1 + a2 + a3;
  csum[t] = s;
  __syncthreads();
  for (int off = 1; off < 256; off <<= 1) {
    int v = (t >= off) ? csum[t - off] : 0;
    __syncthreads();
    csum[t] += v;
    __syncthreads();
  }
  int base = csum[t] - s;
  if (i0 + 0 < NBKT) lstart[i0 + 0] = base; base += a0;
  if (i0 + 1 < NBKT) lstart[i0 + 1] = base; base += a1;
  if (i0 + 2 < NBKT) lstart[i0 + 2] = base; base += a2;
  if (i0 + 3 < NBKT) lstart[i0 + 3] = base;
  __syncthreads();

  for (int i = t; i < NBKT; i += 256) {
    int c = lhist[i];
    int off = c ? atomicAdd(&gcur[i], c) : 0;
    gb[i] = i * BCAP + off;
    lcur[i] = lstart[i];
  }
  __syncthreads();

  for (int k = t; k < ecnt; k += 256) {
    int d  = dst[e0 + k];
    int sr = src[e0 + k];
    float w = wgt[e0 + k];
    int b = d >> 7;
    int p = atomicAdd(&lcur[b], 1);
    staged[p] = ((unsigned long long)__float_as_uint(w) << 32) |
                ((unsigned)(d & 127) << 17) | (unsigned)sr;
    sbkt[p] = (unsigned short)b;
  }
  __syncthreads();

  for (int j = t; j < ecnt; j += 256) {
    int b = sbkt[j];
    int addr = gb[b] + (j - lstart[b]);
    if (addr < (b + 1) * BCAP) region[addr] = staged[j];  // overflow guard (never fires)
  }
}

// ---- pass B: per-bucket in-place counting sort by local dst + rowse ----
__global__ __launch_bounds__(256) void csrB_kernel(unsigned long long* __restrict__ region,
                                                   const int* __restrict__ gcur,
                                                   int2* __restrict__ rowse) {
  __shared__ unsigned long long lcsr[BCAP];
  __shared__ int lhist[128], loff[128], lcur[128];
  const int t = threadIdx.x;
  const int b = blockIdx.x;
  const int cnt = min(gcur[b], BCAP);
  const int base = b * BCAP;

  if (t < 128) lhist[t] = 0;
  __syncthreads();
  for (int j = t; j < cnt; j += 256) {
    unsigned lo = (unsigned)(region[base + j] & 0xffffffffu);
    atomicAdd(&lhist[(lo >> 17) & 127], 1);
  }
  __syncthreads();
  if (t < 128) loff[t] = lhist[t];
  __syncthreads();
  for (int off = 1; off < 128; off <<= 1) {
    int v = (t >= off && t < 128) ? loff[t - off] : 0;
    __syncthreads();
    if (t < 128) loff[t] += v;
    __syncthreads();
  }
  if (t < 128) { loff[t] -= lhist[t]; lcur[t] = loff[t]; }
  __syncthreads();
  for (int j = t; j < cnt; j += 256) {
    unsigned long long e = region[base + j];
    int dl = (int)((e >> 17) & 127);
    int p = atomicAdd(&lcur[dl], 1);
    lcsr[p] = e;
  }
  __syncthreads();
  for (int j = t; j < cnt; j += 256) region[base + j] = lcsr[j];
  if (t < 128) {
    int gd = b * 128 + t;
    if (gd < N_NODES) rowse[gd] = make_int2(base + loff[t], base + lcur[t]);
  }
}

// -------- gather: 1 wave per node, lane owns 4 cols, 8-edge MLP ----------
__global__ __launch_bounds__(64) void gather_kernel(const unsigned long long* __restrict__ packed,
                                                    const int2* __restrict__ rowse,
                                                    const unsigned short* __restrict__ sup,
                                                    const float* __restrict__ bias,
                                                    float* __restrict__ out) {
  int n = blockIdx.x;
  int l = threadIdx.x;
  int c0 = l * 4;
  int2 se = rowse[n];
  int start = se.x, end = se.y;
  float4 bv = *(const float4*)(bias + c0);
  float a0 = bv.x, a1 = bv.y, a2 = bv.z, a3 = bv.w;

  int i = start;
  // main: 8 independent sup-row loads in flight per wave
  for (; i + 8 <= end; i += 8) {
    unsigned long long m[8];
#pragma unroll
    for (int j = 0; j < 8; ++j) m[j] = __builtin_nontemporal_load(&packed[i + j]);
    uint2 p[8];
#pragma unroll
    for (int j = 0; j < 8; ++j) {
      int s = (int)(m[j] & 0x1ffffu);
      p[j] = *(const uint2*)(sup + (size_t)s * 256 + c0);
    }
#pragma unroll
    for (int j = 0; j < 8; ++j) {
      float w = __uint_as_float((unsigned)(m[j] >> 32));
      a0 = fmaf(w, bflo(p[j].x), a0);
      a1 = fmaf(w, bfhi(p[j].x), a1);
      a2 = fmaf(w, bflo(p[j].y), a2);
      a3 = fmaf(w, bfhi(p[j].y), a3);
    }
  }
  for (; i < end; ++i) {
    unsigned long long m0 = __builtin_nontemporal_load(&packed[i]);
    int   s0 = (int)(m0 & 0x1ffffu);
    float w0 = __uint_as_float((unsigned)(m0 >> 32));
    uint2 p0 = *(const uint2*)(sup + (size_t)s0 * 256 + c0);
    a0 = fmaf(w0, bflo(p0.x), a0);
    a1 = fmaf(w0, bfhi(p0.x), a1);
    a2 = fmaf(w0, bflo(p0.y), a2);
    a3 = fmaf(w0, bfhi(p0.y), a3);
  }
  f32x4 o = {a0, a1, a2, a3};
  __builtin_nontemporal_store(o, (f32x4*)(out + (size_t)n * 256 + c0));
}

extern "C" void kernel_launch(void* const* d_in, const int* in_sizes, int n_in,
                              void* d_out, int out_size, void* d_ws, size_t ws_size,
                              hipStream_t stream) {
  const float* x        = (const float*)d_in[0];
  const int*   edge_src = (const int*)d_in[1];
  const int*   edge_dst = (const int*)d_in[2];
  const float* edge_w   = (const float*)d_in[3];
  const float* weight   = (const float*)d_in[4];
  const float* bias     = (const float*)d_in[5];
  float* out = (float*)d_out;

  char* ws = (char*)d_ws;
  size_t off = 0;
  auto alloc = [&](size_t bytes) -> void* {
    void* p = ws + off;
    off = (off + bytes + 255) & ~(size_t)255;
    return p;
  };

  unsigned short* xb  = (unsigned short*)alloc((size_t)M_PAD * 256 * 2);  // 51.25 MB
  unsigned short* wt  = (unsigned short*)alloc(256 * 256 * 2);
  unsigned short* sup = (unsigned short*)alloc((size_t)M_PAD * 256 * 2);  // 51.25 MB

  // region/gcur/rowse alias xb (dead after gemm); region = 782*4608*8 = 28.84 MB
  char* xbb = (char*)xb;
  unsigned long long* region = (unsigned long long*)xbb;
  int*  gcur  = (int*)(xbb + (29u << 20));
  int2* rowse = (int2*)(xbb + (30u << 20));

  conv_x_kernel<<<25000, 256, 0, stream>>>(x, xb);
  conv_w_kernel<<<256, 256, 0, stream>>>(weight, wt);
  gemm_kernel<<<dim3(782, 2), 256, 0, stream>>>(xb, wt, sup);
  (void)hipMemsetAsync(gcur, 0, NBKT * 4, stream);    // after gemm: gcur aliases xb
  binA_kernel<<<(N_EDGES + EPB_A - 1) / EPB_A, 256, 0, stream>>>(edge_src, edge_dst, edge_w,
                                                                 gcur, region);
  csrB_kernel<<<NBKT, 256, 0, stream>>>(region, gcur, rowse);
  gather_kernel<<<N_NODES, 64, 0, stream>>>(region, rowse, sup, bias, out);
}